// Round 1
// baseline (737.374 us; speedup 1.0000x reference)
//
#include <hip/hip_runtime.h>
#include <cfloat>

#define BB 32
#define NN 2048
#define DD 128
#define RM 64     // rows per block
#define CN 64     // cols per tile
#define LSTR 68   // LDS k-major leading stride (floats): 64 data + 4 pad (keeps f4 align, breaks bank strides)

struct Cand { float sc; int ix; };

__global__ __launch_bounds__(256) void sq_kernel(const float* __restrict__ x,
                                                 float* __restrict__ sq) {
    int t = blockIdx.x * 256 + threadIdx.x;
    int row = t >> 2;   // 0..B*N-1
    int q = t & 3;      // 4 threads per row, 32 dims each
    const float4* xp = reinterpret_cast<const float4*>(x + (size_t)row * DD + q * 32);
    float acc = 0.f;
#pragma unroll
    for (int i = 0; i < 8; ++i) {
        float4 v = xp[i];
        acc += v.x * v.x + v.y * v.y + v.z * v.z + v.w * v.w;
    }
    acc += __shfl_xor(acc, 1);
    acc += __shfl_xor(acc, 2);
    if (q == 0) sq[row] = acc;
}

__global__ __launch_bounds__(256) void knn_kernel(const float* __restrict__ x,
        const float* __restrict__ sqv, const float* __restrict__ strength,
        float* __restrict__ out) {
    // k-major LDS tiles: As[k*LSTR + r], Bs[k*LSTR + c]
    __shared__ __align__(16) float As[DD * LSTR];   // 34816 B
    __shared__ __align__(16) float Bs[DD * LSTR];   // 34816 B (aliased as merge buffer later)
    __shared__ int cand8[RM * 8];                   // 2 KB
    __shared__ double refd[RM * 8];                 // 4 KB
    __shared__ int best3[RM * 3];                   // 768 B  -> total ~76.5 KB => 2 blocks/CU

    const int b = blockIdx.y;
    const int row0 = blockIdx.x * RM;
    const int tid = threadIdx.x;
    const int ty = tid >> 4;   // 0..15 -> rows 4*ty..4*ty+3
    const int tx = tid & 15;   // 0..15 -> cols 4*tx..4*tx+3
    const float* __restrict__ xb = x + (size_t)b * NN * DD;

    // ---- stage A tile (rows row0..row0+63), transposed to k-major ----
    // thread handles (k, row-group): 4 strided dword global loads -> one b128 LDS write
#pragma unroll
    for (int l = 0; l < 8; ++l) {
        int flat = l * 256 + tid;      // 0..2047
        int k = flat & 127;
        int rg = flat >> 7;            // 0..15
        const float* src = xb + (size_t)(row0 + rg * 4) * DD + k;
        float4 v;
        v.x = src[0 * DD]; v.y = src[1 * DD]; v.z = src[2 * DD]; v.w = src[3 * DD];
        *reinterpret_cast<float4*>(As + k * LSTR + rg * 4) = v;
    }

    // per-thread top-4 (score, col) for each of 4 owned rows
    float ts[4][4]; int ti[4][4];
#pragma unroll
    for (int i = 0; i < 4; ++i)
#pragma unroll
        for (int q = 0; q < 4; ++q) { ts[i][q] = FLT_MAX; ti[i][q] = 0x7fffffff; }

    for (int ct = 0; ct < NN / CN; ++ct) {
        __syncthreads();   // previous tile's compute done reading Bs
#pragma unroll
        for (int l = 0; l < 8; ++l) {
            int flat = l * 256 + tid;
            int k = flat & 127;
            int cg = flat >> 7;
            const float* src = xb + (size_t)(ct * CN + cg * 4) * DD + k;
            float4 v;
            v.x = src[0 * DD]; v.y = src[1 * DD]; v.z = src[2 * DD]; v.w = src[3 * DD];
            *reinterpret_cast<float4*>(Bs + k * LSTR + cg * 4) = v;
        }
        __syncthreads();

        float acc[4][4];
#pragma unroll
        for (int i = 0; i < 4; ++i)
#pragma unroll
            for (int j = 0; j < 4; ++j) acc[i][j] = 0.f;

#pragma unroll 4
        for (int k = 0; k < DD; ++k) {
            float4 a  = *reinterpret_cast<const float4*>(As + k * LSTR + 4 * ty);
            float4 bb = *reinterpret_cast<const float4*>(Bs + k * LSTR + 4 * tx);
            float av[4]  = {a.x, a.y, a.z, a.w};
            float bvv[4] = {bb.x, bb.y, bb.z, bb.w};
#pragma unroll
            for (int i = 0; i < 4; ++i)
#pragma unroll
                for (int j = 0; j < 4; ++j)
                    acc[i][j] = fmaf(av[i], bvv[j], acc[i][j]);
        }

        // fold into per-row running top-4 by approx score sq_c - 2*dot (sq_r constant per row)
        float4 sq4 = *reinterpret_cast<const float4*>(sqv + (size_t)b * NN + ct * CN + 4 * tx);
        float sqc[4] = {sq4.x, sq4.y, sq4.z, sq4.w};
        int colbase = ct * CN + 4 * tx;
#pragma unroll
        for (int i = 0; i < 4; ++i) {
            int gr = row0 + 4 * ty + i;
#pragma unroll
            for (int j = 0; j < 4; ++j) {
                float sc = sqc[j] - 2.f * acc[i][j];
                int col = colbase + j;
                // strict < : on tie the earlier (lower col, since scan is ascending) survives
                if (col != gr && sc < ts[i][3]) {
                    ts[i][3] = sc; ti[i][3] = col;
#pragma unroll
                    for (int q = 3; q >= 1; --q) {
                        if (ts[i][q] < ts[i][q - 1]) {
                            float tf = ts[i][q]; ts[i][q] = ts[i][q - 1]; ts[i][q - 1] = tf;
                            int tn = ti[i][q]; ti[i][q] = ti[i][q - 1]; ti[i][q - 1] = tn;
                        }
                    }
                }
            }
        }
    }

    __syncthreads();   // all compute reads of Bs done; alias it as the merge buffer
    Cand* mg = reinterpret_cast<Cand*>(Bs);
#pragma unroll
    for (int i = 0; i < 4; ++i) {
        int r = 4 * ty + i;
#pragma unroll
        for (int q = 0; q < 4; ++q) {
            Cand c; c.sc = ts[i][q]; c.ix = ti[i][q];
            mg[(r * 16 + tx) * 4 + q] = c;
        }
    }
    __syncthreads();

    // ---- merge: per row, scan 64 candidates, keep approx-top-8 ----
    if (tid < RM) {
        int r = tid;
        float bs8[8]; int bi8[8];
#pragma unroll
        for (int q = 0; q < 8; ++q) { bs8[q] = FLT_MAX; bi8[q] = 0x7fffffff; }
        for (int ee = 0; ee < 64; ++ee) {
            Cand c = mg[r * 64 + ((r + ee) & 63)];   // staggered start: avoids 32-way bank conflict
            if (c.sc < bs8[7] || (c.sc == bs8[7] && c.ix < bi8[7])) {
                bs8[7] = c.sc; bi8[7] = c.ix;
#pragma unroll
                for (int q = 7; q >= 1; --q) {
                    bool sw = (bs8[q] < bs8[q - 1]) ||
                              (bs8[q] == bs8[q - 1] && bi8[q] < bi8[q - 1]);
                    if (sw) {
                        float tf = bs8[q]; bs8[q] = bs8[q - 1]; bs8[q - 1] = tf;
                        int tn = bi8[q]; bi8[q] = bi8[q - 1]; bi8[q - 1] = tn;
                    }
                }
            }
        }
#pragma unroll
        for (int q = 0; q < 8; ++q) cand8[r * 8 + q] = bi8[q];
    }
    __syncthreads();

    // ---- refine: exact fp64 squared distance for the 8 survivors per row ----
    {
        int r = tid >> 2, q4 = tid & 3;   // 4 threads per row, 2 candidates each
        int c0 = cand8[r * 8 + q4 * 2 + 0];
        int c1 = cand8[r * 8 + q4 * 2 + 1];
        const float* p0 = xb + (size_t)c0 * DD;
        const float* p1 = xb + (size_t)c1 * DD;
        double a0 = 0.0, a1 = 0.0;
#pragma unroll 4
        for (int d4 = 0; d4 < 32; ++d4) {
            float4 v0 = *reinterpret_cast<const float4*>(p0 + d4 * 4);
            float4 v1 = *reinterpret_cast<const float4*>(p1 + d4 * 4);
            float aw0 = As[(d4 * 4 + 0) * LSTR + r];
            float aw1 = As[(d4 * 4 + 1) * LSTR + r];
            float aw2 = As[(d4 * 4 + 2) * LSTR + r];
            float aw3 = As[(d4 * 4 + 3) * LSTR + r];
            double d;
            d = (double)aw0 - (double)v0.x; a0 += d * d;
            d = (double)aw1 - (double)v0.y; a0 += d * d;
            d = (double)aw2 - (double)v0.z; a0 += d * d;
            d = (double)aw3 - (double)v0.w; a0 += d * d;
            d = (double)aw0 - (double)v1.x; a1 += d * d;
            d = (double)aw1 - (double)v1.y; a1 += d * d;
            d = (double)aw2 - (double)v1.z; a1 += d * d;
            d = (double)aw3 - (double)v1.w; a1 += d * d;
        }
        refd[r * 8 + q4 * 2 + 0] = a0;
        refd[r * 8 + q4 * 2 + 1] = a1;
    }
    __syncthreads();

    // ---- final top-3 by (exact d2, idx) lexicographic ----
    if (tid < RM) {
        int r = tid;
        double b0 = DBL_MAX, b1 = DBL_MAX, b2 = DBL_MAX;
        int i0 = 0x7fffffff, i1 = 0x7fffffff, i2 = 0x7fffffff;
        for (int e = 0; e < 8; ++e) {
            double dv = refd[r * 8 + e];
            int ix = cand8[r * 8 + e];
            if (dv < b2 || (dv == b2 && ix < i2)) {
                b2 = dv; i2 = ix;
                if (b1 > b2 || (b1 == b2 && i1 > i2)) { double td = b1; b1 = b2; b2 = td; int tn = i1; i1 = i2; i2 = tn; }
                if (b0 > b1 || (b0 == b1 && i0 > i1)) { double td = b0; b0 = b1; b1 = td; int tn = i0; i0 = i1; i1 = tn; }
            }
        }
        best3[r * 3 + 0] = i0; best3[r * 3 + 1] = i1; best3[r * 3 + 2] = i2;
    }
    __syncthreads();

    // ---- output: (1-s)*x + s*mean(3 neighbors), summed in rank order like the ref ----
    {
        int r = tid >> 2, q = tid & 3;
        float s = fminf(fmaxf(strength[0], 0.f), 1.f);
        const float* pa = xb + (size_t)(row0 + r) * DD + q * 32;
        const float* p1 = xb + (size_t)best3[r * 3 + 0] * DD + q * 32;
        const float* p2 = xb + (size_t)best3[r * 3 + 1] * DD + q * 32;
        const float* p3 = xb + (size_t)best3[r * 3 + 2] * DD + q * 32;
        float* po = out + ((size_t)b * NN + row0 + r) * DD + q * 32;
#pragma unroll
        for (int l = 0; l < 8; ++l) {
            float4 a  = *reinterpret_cast<const float4*>(pa + l * 4);
            float4 n1 = *reinterpret_cast<const float4*>(p1 + l * 4);
            float4 n2 = *reinterpret_cast<const float4*>(p2 + l * 4);
            float4 n3 = *reinterpret_cast<const float4*>(p3 + l * 4);
            float4 o;
            o.x = (1.f - s) * a.x + s * ((n1.x + n2.x + n3.x) / 3.f);
            o.y = (1.f - s) * a.y + s * ((n1.y + n2.y + n3.y) / 3.f);
            o.z = (1.f - s) * a.z + s * ((n1.z + n2.z + n3.z) / 3.f);
            o.w = (1.f - s) * a.w + s * ((n1.w + n2.w + n3.w) / 3.f);
            *reinterpret_cast<float4*>(po + l * 4) = o;
        }
    }
}

extern "C" void kernel_launch(void* const* d_in, const int* in_sizes, int n_in,
                              void* d_out, int out_size, void* d_ws, size_t ws_size,
                              hipStream_t stream) {
    const float* x = (const float*)d_in[0];
    const float* strength = (const float*)d_in[1];
    float* out = (float*)d_out;
    float* sq = (float*)d_ws;   // B*N floats = 256 KB of scratch

    sq_kernel<<<dim3((BB * NN * 4) / 256), 256, 0, stream>>>(x, sq);
    knn_kernel<<<dim3(NN / RM, BB), 256, 0, stream>>>(x, sq, strength, out);
}

// Round 2
// 430.007 us; speedup vs baseline: 1.7148x; 1.7148x over previous
//
#include <hip/hip_runtime.h>
#include <cfloat>

#define BB 32
#define NN 2048
#define DD 128
#define RM 64     // rows per block (4 waves x 16)
#define CN 64     // cols per tile
#define KST 136   // bf16 elems per LDS tile row: 128 + 8 pad (keeps 16B align; odd 16B-group stride)

typedef __attribute__((ext_vector_type(8))) short short8;
typedef __attribute__((ext_vector_type(4))) float float4v;

struct Cand { float sc; int ix; };

__device__ __forceinline__ unsigned short f2bf(float f) {
    unsigned int u = __builtin_bit_cast(unsigned int, f);
    u += 0x7FFFu + ((u >> 16) & 1u);   // RNE
    return (unsigned short)(u >> 16);
}

__global__ __launch_bounds__(256) void sq_kernel(const float* __restrict__ x,
                                                 float* __restrict__ sq) {
    int t = blockIdx.x * 256 + threadIdx.x;
    int row = t >> 2;
    int q = t & 3;
    const float4* xp = reinterpret_cast<const float4*>(x + (size_t)row * DD + q * 32);
    float acc = 0.f;
#pragma unroll
    for (int i = 0; i < 8; ++i) {
        float4 v = xp[i];
        acc += v.x * v.x + v.y * v.y + v.z * v.z + v.w * v.w;
    }
    acc += __shfl_xor(acc, 1);
    acc += __shfl_xor(acc, 2);
    if (q == 0) sq[row] = acc;
}

__global__ __launch_bounds__(256, 3) void knn_kernel(const float* __restrict__ x,
        const float* __restrict__ sqv, const float* __restrict__ strength,
        float* __restrict__ out) {
    __shared__ __align__(16) unsigned short tiles[2 * RM * KST]; // 34816 B (mg aliases this)
    __shared__ int cand8[RM * 8];     // 2 KB
    __shared__ double refd[RM * 8];   // 4 KB
    __shared__ int best3[RM * 3];     // 768 B   => ~41.7 KB total => 3 blocks/CU

    unsigned short* As = tiles;
    unsigned short* Bs = tiles + RM * KST;

    const int b = blockIdx.y;
    const int row0 = blockIdx.x * RM;
    const int tid = threadIdx.x;
    const int w = tid >> 6;      // wave 0..3 -> rows 16w..16w+15
    const int lane = tid & 63;
    const int m = lane & 15;     // A-row / B-col / C-col class within 16
    const int quad = lane >> 4;  // k-chunk-of-8 for frags; row-quad for C
    const float* __restrict__ xb = x + (size_t)b * NN * DD;

    // ---- stage A tile (64 rows x 128 k) as bf16, row-major k ----
#pragma unroll
    for (int l = 0; l < 4; ++l) {
        int id = l * 256 + tid;          // 0..1023
        int r = id >> 4;
        int k0 = (id & 15) * 8;
        const float4* src = reinterpret_cast<const float4*>(xb + (size_t)(row0 + r) * DD + k0);
        float4 v0 = src[0], v1 = src[1];
        short8 pk;
        pk[0] = (short)f2bf(v0.x); pk[1] = (short)f2bf(v0.y);
        pk[2] = (short)f2bf(v0.z); pk[3] = (short)f2bf(v0.w);
        pk[4] = (short)f2bf(v1.x); pk[5] = (short)f2bf(v1.y);
        pk[6] = (short)f2bf(v1.z); pk[7] = (short)f2bf(v1.w);
        *reinterpret_cast<short8*>(As + r * KST + k0) = pk;
    }
    __syncthreads();

    // ---- persistent A fragments: A[m=lane&15][k = kc*32 + quad*8 + j] ----
    short8 afrag[4];
#pragma unroll
    for (int kc = 0; kc < 4; ++kc)
        afrag[kc] = *reinterpret_cast<const short8*>(As + (16 * w + m) * KST + kc * 32 + quad * 8);

    // per-(lane,reg) running top-4: reg indexes the 4 owned C-rows (quad*4+reg)
    float ts[4][4]; int ti[4][4];
#pragma unroll
    for (int i = 0; i < 4; ++i)
#pragma unroll
        for (int q = 0; q < 4; ++q) { ts[i][q] = FLT_MAX; ti[i][q] = 0x7fffffff; }

    for (int ct = 0; ct < NN / CN; ++ct) {
        __syncthreads();   // previous tile's frag reads done
#pragma unroll
        for (int l = 0; l < 4; ++l) {
            int id = l * 256 + tid;
            int c = id >> 4;
            int k0 = (id & 15) * 8;
            const float4* src = reinterpret_cast<const float4*>(xb + (size_t)(ct * CN + c) * DD + k0);
            float4 v0 = src[0], v1 = src[1];
            short8 pk;
            pk[0] = (short)f2bf(v0.x); pk[1] = (short)f2bf(v0.y);
            pk[2] = (short)f2bf(v0.z); pk[3] = (short)f2bf(v0.w);
            pk[4] = (short)f2bf(v1.x); pk[5] = (short)f2bf(v1.y);
            pk[6] = (short)f2bf(v1.z); pk[7] = (short)f2bf(v1.w);
            *reinterpret_cast<short8*>(Bs + c * KST + k0) = pk;
        }
        __syncthreads();

        // ---- 4 independent acc chains (cc inner => no back-to-back mfma dependency) ----
        float4v acc[4];
#pragma unroll
        for (int cc = 0; cc < 4; ++cc) acc[cc] = (float4v){0.f, 0.f, 0.f, 0.f};
#pragma unroll
        for (int kc = 0; kc < 4; ++kc) {
#pragma unroll
            for (int cc = 0; cc < 4; ++cc) {
                short8 bfrag = *reinterpret_cast<const short8*>(
                    Bs + (cc * 16 + m) * KST + kc * 32 + quad * 8);
                acc[cc] = __builtin_amdgcn_mfma_f32_16x16x32_bf16(afrag[kc], bfrag, acc[cc], 0, 0, 0);
            }
        }

        // ---- epilogue: score = sq_c - 2*dot ; fold into per-lane top-4 ----
#pragma unroll
        for (int cc = 0; cc < 4; ++cc) {
            int col = ct * CN + cc * 16 + m;
            float sqc = sqv[(size_t)b * NN + col];
#pragma unroll
            for (int reg = 0; reg < 4; ++reg) {
                float sc = fmaf(-2.f, acc[cc][reg], sqc);
                int grow = row0 + 16 * w + quad * 4 + reg;
                if (col != grow && sc < ts[reg][3]) {
                    ts[reg][3] = sc; ti[reg][3] = col;
#pragma unroll
                    for (int q = 3; q >= 1; --q) {
                        if (ts[reg][q] < ts[reg][q - 1]) {
                            float tf = ts[reg][q]; ts[reg][q] = ts[reg][q - 1]; ts[reg][q - 1] = tf;
                            int tn = ti[reg][q]; ti[reg][q] = ti[reg][q - 1]; ti[reg][q - 1] = tn;
                        }
                    }
                }
            }
        }
    }

    __syncthreads();   // all frag reads done; alias tiles as merge buffer
    Cand* mg = reinterpret_cast<Cand*>(tiles);   // 64 rows x 16 classes x 4 = 32 KB
#pragma unroll
    for (int reg = 0; reg < 4; ++reg) {
        int rl = 16 * w + quad * 4 + reg;
#pragma unroll
        for (int q = 0; q < 4; ++q) {
            Cand c; c.sc = ts[reg][q]; c.ix = ti[reg][q];
            mg[(rl * 16 + m) * 4 + q] = c;
        }
    }
    __syncthreads();

    // ---- merge: per row scan 64 candidates -> approx-top-8 ----
    if (tid < RM) {
        int r = tid;
        float bs8[8]; int bi8[8];
#pragma unroll
        for (int q = 0; q < 8; ++q) { bs8[q] = FLT_MAX; bi8[q] = 0x7fffffff; }
        for (int ee = 0; ee < 64; ++ee) {
            Cand c = mg[r * 64 + ((r + ee) & 63)];
            if (c.sc < bs8[7] || (c.sc == bs8[7] && c.ix < bi8[7])) {
                bs8[7] = c.sc; bi8[7] = c.ix;
#pragma unroll
                for (int q = 7; q >= 1; --q) {
                    bool sw = (bs8[q] < bs8[q - 1]) ||
                              (bs8[q] == bs8[q - 1] && bi8[q] < bi8[q - 1]);
                    if (sw) {
                        float tf = bs8[q]; bs8[q] = bs8[q - 1]; bs8[q - 1] = tf;
                        int tn = bi8[q]; bi8[q] = bi8[q - 1]; bi8[q - 1] = tn;
                    }
                }
            }
        }
#pragma unroll
        for (int q = 0; q < 8; ++q) cand8[r * 8 + q] = bi8[q];
    }
    __syncthreads();

    // ---- refine: exact fp64 distance for 8 survivors/row (reads original fp32 from global) ----
    {
        int r = tid >> 2, q4 = tid & 3;
        int c0 = cand8[r * 8 + q4 * 2 + 0];
        int c1 = cand8[r * 8 + q4 * 2 + 1];
        const float* p0 = xb + (size_t)c0 * DD;
        const float* p1 = xb + (size_t)c1 * DD;
        const float* pr = xb + (size_t)(row0 + r) * DD;
        double a0 = 0.0, a1 = 0.0;
#pragma unroll 4
        for (int d4 = 0; d4 < 32; ++d4) {
            float4 wv = *reinterpret_cast<const float4*>(pr + d4 * 4);
            float4 v0 = *reinterpret_cast<const float4*>(p0 + d4 * 4);
            float4 v1 = *reinterpret_cast<const float4*>(p1 + d4 * 4);
            double d;
            d = (double)wv.x - (double)v0.x; a0 += d * d;
            d = (double)wv.y - (double)v0.y; a0 += d * d;
            d = (double)wv.z - (double)v0.z; a0 += d * d;
            d = (double)wv.w - (double)v0.w; a0 += d * d;
            d = (double)wv.x - (double)v1.x; a1 += d * d;
            d = (double)wv.y - (double)v1.y; a1 += d * d;
            d = (double)wv.z - (double)v1.z; a1 += d * d;
            d = (double)wv.w - (double)v1.w; a1 += d * d;
        }
        refd[r * 8 + q4 * 2 + 0] = a0;
        refd[r * 8 + q4 * 2 + 1] = a1;
    }
    __syncthreads();

    // ---- final top-3 by (exact d2, idx) ----
    if (tid < RM) {
        int r = tid;
        double b0 = DBL_MAX, b1 = DBL_MAX, b2 = DBL_MAX;
        int i0 = 0x7fffffff, i1 = 0x7fffffff, i2 = 0x7fffffff;
        for (int e = 0; e < 8; ++e) {
            double dv = refd[r * 8 + e];
            int ix = cand8[r * 8 + e];
            if (dv < b2 || (dv == b2 && ix < i2)) {
                b2 = dv; i2 = ix;
                if (b1 > b2 || (b1 == b2 && i1 > i2)) { double td = b1; b1 = b2; b2 = td; int tn = i1; i1 = i2; i2 = tn; }
                if (b0 > b1 || (b0 == b1 && i0 > i1)) { double td = b0; b0 = b1; b1 = td; int tn = i0; i0 = i1; i1 = tn; }
            }
        }
        best3[r * 3 + 0] = i0; best3[r * 3 + 1] = i1; best3[r * 3 + 2] = i2;
    }
    __syncthreads();

    // ---- output: (1-s)*x + s*mean(3 neighbors) ----
    {
        int r = tid >> 2, q = tid & 3;
        float s = fminf(fmaxf(strength[0], 0.f), 1.f);
        const float* pa = xb + (size_t)(row0 + r) * DD + q * 32;
        const float* p1 = xb + (size_t)best3[r * 3 + 0] * DD + q * 32;
        const float* p2 = xb + (size_t)best3[r * 3 + 1] * DD + q * 32;
        const float* p3 = xb + (size_t)best3[r * 3 + 2] * DD + q * 32;
        float* po = out + ((size_t)b * NN + row0 + r) * DD + q * 32;
#pragma unroll
        for (int l = 0; l < 8; ++l) {
            float4 a  = *reinterpret_cast<const float4*>(pa + l * 4);
            float4 n1 = *reinterpret_cast<const float4*>(p1 + l * 4);
            float4 n2 = *reinterpret_cast<const float4*>(p2 + l * 4);
            float4 n3 = *reinterpret_cast<const float4*>(p3 + l * 4);
            float4 o;
            o.x = (1.f - s) * a.x + s * ((n1.x + n2.x + n3.x) / 3.f);
            o.y = (1.f - s) * a.y + s * ((n1.y + n2.y + n3.y) / 3.f);
            o.z = (1.f - s) * a.z + s * ((n1.z + n2.z + n3.z) / 3.f);
            o.w = (1.f - s) * a.w + s * ((n1.w + n2.w + n3.w) / 3.f);
            *reinterpret_cast<float4*>(po + l * 4) = o;
        }
    }
}

extern "C" void kernel_launch(void* const* d_in, const int* in_sizes, int n_in,
                              void* d_out, int out_size, void* d_ws, size_t ws_size,
                              hipStream_t stream) {
    const float* x = (const float*)d_in[0];
    const float* strength = (const float*)d_in[1];
    float* out = (float*)d_out;
    float* sq = (float*)d_ws;   // B*N floats = 256 KB scratch

    sq_kernel<<<dim3((BB * NN * 4) / 256), 256, 0, stream>>>(x, sq);
    knn_kernel<<<dim3(NN / RM, BB), 256, 0, stream>>>(x, sq, strength, out);
}

// Round 3
// 276.588 us; speedup vs baseline: 2.6660x; 1.5547x over previous
//
#include <hip/hip_runtime.h>
#include <cfloat>

#define BB 32
#define NN 2048
#define DD 128
#define RM 64     // rows per block (4 waves x 16)
#define CN 64     // cols per tile

typedef __attribute__((ext_vector_type(8))) short short8;
typedef __attribute__((ext_vector_type(4))) float float4v;

struct Cand { float sc; int ix; };

__device__ __forceinline__ unsigned short f2bf(float f) {
    unsigned int u = __builtin_bit_cast(unsigned int, f);
    u += 0x7FFFu + ((u >> 16) & 1u);   // RNE
    return (unsigned short)(u >> 16);
}

// async global->LDS, 16B per lane. LDS dest is wave-uniform base + lane*16.
__device__ __forceinline__ void gl2lds16(const unsigned short* g, unsigned short* l) {
    __builtin_amdgcn_global_load_lds(
        (const __attribute__((address_space(1))) void*)g,
        (__attribute__((address_space(3))) void*)l, 16, 0, 0);
}

// fused: sq = sum(x^2) per row, and bf16 copy of x into workspace
__global__ __launch_bounds__(256) void prep_kernel(const float* __restrict__ x,
        unsigned short* __restrict__ xb16, float* __restrict__ sq) {
    int t = blockIdx.x * 256 + threadIdx.x;
    int row = t >> 2;
    int q = t & 3;   // 32 floats per thread
    const float4* xp = reinterpret_cast<const float4*>(x + (size_t)row * DD + q * 32);
    unsigned short* op = xb16 + (size_t)row * DD + q * 32;
    float acc = 0.f;
#pragma unroll
    for (int i = 0; i < 4; ++i) {
        float4 v0 = xp[2 * i], v1 = xp[2 * i + 1];
        acc += v0.x * v0.x + v0.y * v0.y + v0.z * v0.z + v0.w * v0.w;
        acc += v1.x * v1.x + v1.y * v1.y + v1.z * v1.z + v1.w * v1.w;
        short8 pk;
        pk[0] = (short)f2bf(v0.x); pk[1] = (short)f2bf(v0.y);
        pk[2] = (short)f2bf(v0.z); pk[3] = (short)f2bf(v0.w);
        pk[4] = (short)f2bf(v1.x); pk[5] = (short)f2bf(v1.y);
        pk[6] = (short)f2bf(v1.z); pk[7] = (short)f2bf(v1.w);
        *reinterpret_cast<short8*>(op + i * 8) = pk;
    }
    acc += __shfl_xor(acc, 1);
    acc += __shfl_xor(acc, 2);
    if (q == 0) sq[row] = acc;
}

// fallback prep when ws too small for the bf16 copy
__global__ __launch_bounds__(256) void sq_kernel(const float* __restrict__ x,
                                                 float* __restrict__ sq) {
    int t = blockIdx.x * 256 + threadIdx.x;
    int row = t >> 2;
    int q = t & 3;
    const float4* xp = reinterpret_cast<const float4*>(x + (size_t)row * DD + q * 32);
    float acc = 0.f;
#pragma unroll
    for (int i = 0; i < 8; ++i) {
        float4 v = xp[i];
        acc += v.x * v.x + v.y * v.y + v.z * v.z + v.w * v.w;
    }
    acc += __shfl_xor(acc, 1);
    acc += __shfl_xor(acc, 2);
    if (q == 0) sq[row] = acc;
}

// LDS tile layout: row r (0..63), 16 chunks of 8 bf16 (16B). chunk c stored at
// position p = c ^ (r & 7)  ->  addr shorts = r*128 + p*8.  No pad (KST=128):
// frag reads then spread over all 8 bank-quads per lane-octet.
template<bool PRE>
__global__ __launch_bounds__(256, 4) void knn_kernel(const float* __restrict__ x,
        const unsigned short* __restrict__ xb16g,
        const float* __restrict__ sqv, const float* __restrict__ strength,
        float* __restrict__ out) {
    __shared__ __align__(16) unsigned short tiles[2 * RM * DD]; // 32 KB (mg aliases)
    __shared__ int cand8[RM * 8];     // 2 KB
    __shared__ double refd[RM * 8];   // 4 KB
    __shared__ int best3[RM * 3];     // 768 B  => 38.75 KB => 4 blocks/CU

    unsigned short* As = tiles;
    unsigned short* Bs = tiles + RM * DD;

    const int b = blockIdx.y;
    const int row0 = blockIdx.x * RM;
    const int tid = threadIdx.x;
    const int w = tid >> 6;
    const int lane = tid & 63;
    const int m = lane & 15;
    const int quad = lane >> 4;
    const float* __restrict__ xb = x + (size_t)b * NN * DD;
    const unsigned short* __restrict__ gb = PRE ? xb16g + (size_t)b * NN * DD : nullptr;

    // ---- stage A tile (64 rows x 128 k) ----
    if constexpr (PRE) {
#pragma unroll
        for (int l = 0; l < 4; ++l) {
            int f = (l * 4 + w) * 64 + lane;     // chunk index 0..1023
            int r = f >> 4, p = f & 15;
            int c = p ^ (r & 7);                 // gather the chunk that belongs at p
            gl2lds16(gb + (size_t)(row0 + r) * DD + c * 8, As + (l * 4 + w) * 512);
        }
    } else {
#pragma unroll
        for (int l = 0; l < 4; ++l) {
            int id = l * 256 + tid;
            int r = id >> 4, c = id & 15, p = c ^ (r & 7);
            const float4* src = reinterpret_cast<const float4*>(xb + (size_t)(row0 + r) * DD + c * 8);
            float4 v0 = src[0], v1 = src[1];
            short8 pk;
            pk[0] = (short)f2bf(v0.x); pk[1] = (short)f2bf(v0.y);
            pk[2] = (short)f2bf(v0.z); pk[3] = (short)f2bf(v0.w);
            pk[4] = (short)f2bf(v1.x); pk[5] = (short)f2bf(v1.y);
            pk[6] = (short)f2bf(v1.z); pk[7] = (short)f2bf(v1.w);
            *reinterpret_cast<short8*>(As + r * DD + p * 8) = pk;
        }
    }
    __syncthreads();

    // ---- persistent A frags: A[m][kc*32 + quad*8 + j], swizzled chunk lookup ----
    short8 afrag[4];
#pragma unroll
    for (int kc = 0; kc < 4; ++kc) {
        int rl = 16 * w + m;
        int p = (kc * 4 + quad) ^ (m & 7);
        afrag[kc] = *reinterpret_cast<const short8*>(As + rl * DD + p * 8);
    }

    float ts[4][4]; int ti[4][4];
#pragma unroll
    for (int i = 0; i < 4; ++i)
#pragma unroll
        for (int q = 0; q < 4; ++q) { ts[i][q] = FLT_MAX; ti[i][q] = 0x7fffffff; }

    for (int ct = 0; ct < NN / CN; ++ct) {
        // hoist sq loads (global, independent of barriers) for latency hiding
        float sqc[4];
#pragma unroll
        for (int cc = 0; cc < 4; ++cc)
            sqc[cc] = sqv[(size_t)b * NN + ct * CN + cc * 16 + m];

        __syncthreads();   // previous tile's frag reads done
        if constexpr (PRE) {
#pragma unroll
            for (int l = 0; l < 4; ++l) {
                int f = (l * 4 + w) * 64 + lane;
                int r = f >> 4, p = f & 15;
                int c = p ^ (r & 7);
                gl2lds16(gb + (size_t)(ct * CN + r) * DD + c * 8, Bs + (l * 4 + w) * 512);
            }
        } else {
#pragma unroll
            for (int l = 0; l < 4; ++l) {
                int id = l * 256 + tid;
                int r = id >> 4, c = id & 15, p = c ^ (r & 7);
                const float4* src = reinterpret_cast<const float4*>(xb + (size_t)(ct * CN + r) * DD + c * 8);
                float4 v0 = src[0], v1 = src[1];
                short8 pk;
                pk[0] = (short)f2bf(v0.x); pk[1] = (short)f2bf(v0.y);
                pk[2] = (short)f2bf(v0.z); pk[3] = (short)f2bf(v0.w);
                pk[4] = (short)f2bf(v1.x); pk[5] = (short)f2bf(v1.y);
                pk[6] = (short)f2bf(v1.z); pk[7] = (short)f2bf(v1.w);
                *reinterpret_cast<short8*>(Bs + r * DD + p * 8) = pk;
            }
        }
        __syncthreads();   // drains vmcnt -> LDS data visible

        float4v acc[4];
#pragma unroll
        for (int cc = 0; cc < 4; ++cc) acc[cc] = (float4v){0.f, 0.f, 0.f, 0.f};
#pragma unroll
        for (int kc = 0; kc < 4; ++kc) {
#pragma unroll
            for (int cc = 0; cc < 4; ++cc) {
                int rl = cc * 16 + m;
                int p = (kc * 4 + quad) ^ (m & 7);
                short8 bfrag = *reinterpret_cast<const short8*>(Bs + rl * DD + p * 8);
                acc[cc] = __builtin_amdgcn_mfma_f32_16x16x32_bf16(afrag[kc], bfrag, acc[cc], 0, 0, 0);
            }
        }

#pragma unroll
        for (int cc = 0; cc < 4; ++cc) {
            int col = ct * CN + cc * 16 + m;
#pragma unroll
            for (int reg = 0; reg < 4; ++reg) {
                float sc = fmaf(-2.f, acc[cc][reg], sqc[cc]);
                int grow = row0 + 16 * w + quad * 4 + reg;
                if (col != grow && sc < ts[reg][3]) {
                    ts[reg][3] = sc; ti[reg][3] = col;
#pragma unroll
                    for (int q = 3; q >= 1; --q) {
                        if (ts[reg][q] < ts[reg][q - 1]) {
                            float tf = ts[reg][q]; ts[reg][q] = ts[reg][q - 1]; ts[reg][q - 1] = tf;
                            int tn = ti[reg][q]; ti[reg][q] = ti[reg][q - 1]; ti[reg][q - 1] = tn;
                        }
                    }
                }
            }
        }
    }

    __syncthreads();
    Cand* mg = reinterpret_cast<Cand*>(tiles);   // 64 rows x 16 x 4 Cands = 32 KB
#pragma unroll
    for (int reg = 0; reg < 4; ++reg) {
        int rl = 16 * w + quad * 4 + reg;
#pragma unroll
        for (int q = 0; q < 4; ++q) {
            Cand c; c.sc = ts[reg][q]; c.ix = ti[reg][q];
            mg[(rl * 16 + m) * 4 + q] = c;
        }
    }
    __syncthreads();

    if (tid < RM) {
        int r = tid;
        float bs8[8]; int bi8[8];
#pragma unroll
        for (int q = 0; q < 8; ++q) { bs8[q] = FLT_MAX; bi8[q] = 0x7fffffff; }
        for (int ee = 0; ee < 64; ++ee) {
            Cand c = mg[r * 64 + ((r + ee) & 63)];
            if (c.sc < bs8[7] || (c.sc == bs8[7] && c.ix < bi8[7])) {
                bs8[7] = c.sc; bi8[7] = c.ix;
#pragma unroll
                for (int q = 7; q >= 1; --q) {
                    bool sw = (bs8[q] < bs8[q - 1]) ||
                              (bs8[q] == bs8[q - 1] && bi8[q] < bi8[q - 1]);
                    if (sw) {
                        float tf = bs8[q]; bs8[q] = bs8[q - 1]; bs8[q - 1] = tf;
                        int tn = bi8[q]; bi8[q] = bi8[q - 1]; bi8[q - 1] = tn;
                    }
                }
            }
        }
#pragma unroll
        for (int q = 0; q < 8; ++q) cand8[r * 8 + q] = bi8[q];
    }
    __syncthreads();

    // ---- refine: exact fp64 distance for 8 survivors/row from original fp32 ----
    {
        int r = tid >> 2, q4 = tid & 3;
        int c0 = cand8[r * 8 + q4 * 2 + 0];
        int c1 = cand8[r * 8 + q4 * 2 + 1];
        const float* p0 = xb + (size_t)c0 * DD;
        const float* p1 = xb + (size_t)c1 * DD;
        const float* pr = xb + (size_t)(row0 + r) * DD;
        double a0 = 0.0, a1 = 0.0;
#pragma unroll 4
        for (int d4 = 0; d4 < 32; ++d4) {
            float4 wv = *reinterpret_cast<const float4*>(pr + d4 * 4);
            float4 v0 = *reinterpret_cast<const float4*>(p0 + d4 * 4);
            float4 v1 = *reinterpret_cast<const float4*>(p1 + d4 * 4);
            double d;
            d = (double)wv.x - (double)v0.x; a0 += d * d;
            d = (double)wv.y - (double)v0.y; a0 += d * d;
            d = (double)wv.z - (double)v0.z; a0 += d * d;
            d = (double)wv.w - (double)v0.w; a0 += d * d;
            d = (double)wv.x - (double)v1.x; a1 += d * d;
            d = (double)wv.y - (double)v1.y; a1 += d * d;
            d = (double)wv.z - (double)v1.z; a1 += d * d;
            d = (double)wv.w - (double)v1.w; a1 += d * d;
        }
        refd[r * 8 + q4 * 2 + 0] = a0;
        refd[r * 8 + q4 * 2 + 1] = a1;
    }
    __syncthreads();

    if (tid < RM) {
        int r = tid;
        double b0 = DBL_MAX, b1 = DBL_MAX, b2 = DBL_MAX;
        int i0 = 0x7fffffff, i1 = 0x7fffffff, i2 = 0x7fffffff;
        for (int e = 0; e < 8; ++e) {
            double dv = refd[r * 8 + e];
            int ix = cand8[r * 8 + e];
            if (dv < b2 || (dv == b2 && ix < i2)) {
                b2 = dv; i2 = ix;
                if (b1 > b2 || (b1 == b2 && i1 > i2)) { double td = b1; b1 = b2; b2 = td; int tn = i1; i1 = i2; i2 = tn; }
                if (b0 > b1 || (b0 == b1 && i0 > i1)) { double td = b0; b0 = b1; b1 = td; int tn = i0; i0 = i1; i1 = tn; }
            }
        }
        best3[r * 3 + 0] = i0; best3[r * 3 + 1] = i1; best3[r * 3 + 2] = i2;
    }
    __syncthreads();

    {
        int r = tid >> 2, q = tid & 3;
        float s = fminf(fmaxf(strength[0], 0.f), 1.f);
        const float* pa = xb + (size_t)(row0 + r) * DD + q * 32;
        const float* p1 = xb + (size_t)best3[r * 3 + 0] * DD + q * 32;
        const float* p2 = xb + (size_t)best3[r * 3 + 1] * DD + q * 32;
        const float* p3 = xb + (size_t)best3[r * 3 + 2] * DD + q * 32;
        float* po = out + ((size_t)b * NN + row0 + r) * DD + q * 32;
#pragma unroll
        for (int l = 0; l < 8; ++l) {
            float4 a  = *reinterpret_cast<const float4*>(pa + l * 4);
            float4 n1 = *reinterpret_cast<const float4*>(p1 + l * 4);
            float4 n2 = *reinterpret_cast<const float4*>(p2 + l * 4);
            float4 n3 = *reinterpret_cast<const float4*>(p3 + l * 4);
            float4 o;
            o.x = (1.f - s) * a.x + s * ((n1.x + n2.x + n3.x) / 3.f);
            o.y = (1.f - s) * a.y + s * ((n1.y + n2.y + n3.y) / 3.f);
            o.z = (1.f - s) * a.z + s * ((n1.z + n2.z + n3.z) / 3.f);
            o.w = (1.f - s) * a.w + s * ((n1.w + n2.w + n3.w) / 3.f);
            *reinterpret_cast<float4*>(po + l * 4) = o;
        }
    }
}

extern "C" void kernel_launch(void* const* d_in, const int* in_sizes, int n_in,
                              void* d_out, int out_size, void* d_ws, size_t ws_size,
                              hipStream_t stream) {
    const float* x = (const float*)d_in[0];
    const float* strength = (const float*)d_in[1];
    float* out = (float*)d_out;
    float* sq = (float*)d_ws;                                   // 256 KB
    unsigned short* xb16 = (unsigned short*)((char*)d_ws + 256 * 1024);  // 16 MB bf16 copy
    const size_t need = 256 * 1024 + (size_t)BB * NN * DD * sizeof(unsigned short);

    if (ws_size >= need) {
        prep_kernel<<<dim3((BB * NN * 4) / 256), 256, 0, stream>>>(x, xb16, sq);
        knn_kernel<true><<<dim3(NN / RM, BB), 256, 0, stream>>>(x, xb16, sq, strength, out);
    } else {
        sq_kernel<<<dim3((BB * NN * 4) / 256), 256, 0, stream>>>(x, sq);
        knn_kernel<false><<<dim3(NN / RM, BB), 256, 0, stream>>>(x, nullptr, sq, strength, out);
    }
}

// Round 4
// 213.462 us; speedup vs baseline: 3.4543x; 1.2957x over previous
//
#include <hip/hip_runtime.h>
#include <cfloat>

#define BB 32
#define NN 2048
#define DD 128
#define RM 64     // rows per block (4 waves x 16)
#define CN 64     // cols per tile

typedef __attribute__((ext_vector_type(8))) short short8;
typedef __attribute__((ext_vector_type(4))) float float4v;

__device__ __forceinline__ unsigned short f2bf(float f) {
    unsigned int u = __builtin_bit_cast(unsigned int, f);
    u += 0x7FFFu + ((u >> 16) & 1u);   // RNE
    return (unsigned short)(u >> 16);
}

__device__ __forceinline__ unsigned int umn(unsigned int a, unsigned int b) { return a < b ? a : b; }
__device__ __forceinline__ unsigned int umx(unsigned int a, unsigned int b) { return a > b ? a : b; }
#define CSU(a, b) { unsigned int _lo = umn(a, b), _hi = umx(a, b); (a) = _lo; (b) = _hi; }

// async global->LDS, 16B per lane. LDS dest is wave-uniform base + lane*16.
__device__ __forceinline__ void gl2lds16(const unsigned short* g, unsigned short* l) {
    __builtin_amdgcn_global_load_lds(
        (const __attribute__((address_space(1))) void*)g,
        (__attribute__((address_space(3))) void*)l, 16, 0, 0);
}

// fused: sq = sum(x^2) per row, and bf16 copy of x into workspace
__global__ __launch_bounds__(256) void prep_kernel(const float* __restrict__ x,
        unsigned short* __restrict__ xb16, float* __restrict__ sq) {
    int t = blockIdx.x * 256 + threadIdx.x;
    int row = t >> 2;
    int q = t & 3;
    const float4* xp = reinterpret_cast<const float4*>(x + (size_t)row * DD + q * 32);
    unsigned short* op = xb16 + (size_t)row * DD + q * 32;
    float acc = 0.f;
#pragma unroll
    for (int i = 0; i < 4; ++i) {
        float4 v0 = xp[2 * i], v1 = xp[2 * i + 1];
        acc += v0.x * v0.x + v0.y * v0.y + v0.z * v0.z + v0.w * v0.w;
        acc += v1.x * v1.x + v1.y * v1.y + v1.z * v1.z + v1.w * v1.w;
        short8 pk;
        pk[0] = (short)f2bf(v0.x); pk[1] = (short)f2bf(v0.y);
        pk[2] = (short)f2bf(v0.z); pk[3] = (short)f2bf(v0.w);
        pk[4] = (short)f2bf(v1.x); pk[5] = (short)f2bf(v1.y);
        pk[6] = (short)f2bf(v1.z); pk[7] = (short)f2bf(v1.w);
        *reinterpret_cast<short8*>(op + i * 8) = pk;
    }
    acc += __shfl_xor(acc, 1);
    acc += __shfl_xor(acc, 2);
    if (q == 0) sq[row] = acc;
}

__global__ __launch_bounds__(256) void sq_kernel(const float* __restrict__ x,
                                                 float* __restrict__ sq) {
    int t = blockIdx.x * 256 + threadIdx.x;
    int row = t >> 2;
    int q = t & 3;
    const float4* xp = reinterpret_cast<const float4*>(x + (size_t)row * DD + q * 32);
    float acc = 0.f;
#pragma unroll
    for (int i = 0; i < 8; ++i) {
        float4 v = xp[i];
        acc += v.x * v.x + v.y * v.y + v.z * v.z + v.w * v.w;
    }
    acc += __shfl_xor(acc, 1);
    acc += __shfl_xor(acc, 2);
    if (q == 0) sq[row] = acc;
}

// LDS tile layout: row r (0..63), 16 chunks of 8 bf16 (16B); chunk c at pos c^(r&7).
template<bool PRE>
__global__ __launch_bounds__(256, 4) void knn_kernel(const float* __restrict__ x,
        const unsigned short* __restrict__ xb16g,
        const float* __restrict__ sqv, const float* __restrict__ strength,
        float* __restrict__ out) {
    __shared__ __align__(16) unsigned short tiles[2 * RM * DD]; // 32 KB
    __shared__ unsigned int cand8[RM * 8];  // 2 KB packed keys (score|col)
    __shared__ double refd[RM * 8];         // 4 KB
    __shared__ int best3[RM * 3];           // 768 B  => 38.75 KB => 4 blocks/CU

    unsigned short* As = tiles;
    unsigned short* Bs = tiles + RM * DD;

    const int b = blockIdx.y;
    const int row0 = blockIdx.x * RM;
    const int tid = threadIdx.x;
    const int w = tid >> 6;
    const int lane = tid & 63;
    const int m = lane & 15;
    const int quad = lane >> 4;
    const float* __restrict__ xb = x + (size_t)b * NN * DD;
    const unsigned short* __restrict__ gb = PRE ? xb16g + (size_t)b * NN * DD : nullptr;

    // ---- stage A tile ----
    if constexpr (PRE) {
#pragma unroll
        for (int l = 0; l < 4; ++l) {
            int f = (l * 4 + w) * 64 + lane;
            int r = f >> 4, p = f & 15;
            int c = p ^ (r & 7);
            gl2lds16(gb + (size_t)(row0 + r) * DD + c * 8, As + (l * 4 + w) * 512);
        }
    } else {
#pragma unroll
        for (int l = 0; l < 4; ++l) {
            int id = l * 256 + tid;
            int r = id >> 4, c = id & 15, p = c ^ (r & 7);
            const float4* src = reinterpret_cast<const float4*>(xb + (size_t)(row0 + r) * DD + c * 8);
            float4 v0 = src[0], v1 = src[1];
            short8 pk;
            pk[0] = (short)f2bf(v0.x); pk[1] = (short)f2bf(v0.y);
            pk[2] = (short)f2bf(v0.z); pk[3] = (short)f2bf(v0.w);
            pk[4] = (short)f2bf(v1.x); pk[5] = (short)f2bf(v1.y);
            pk[6] = (short)f2bf(v1.z); pk[7] = (short)f2bf(v1.w);
            *reinterpret_cast<short8*>(As + r * DD + p * 8) = pk;
        }
    }
    __syncthreads();

    short8 afrag[4];
#pragma unroll
    for (int kc = 0; kc < 4; ++kc) {
        int rl = 16 * w + m;
        int p = (kc * 4 + quad) ^ (m & 7);
        afrag[kc] = *reinterpret_cast<const short8*>(As + rl * DD + p * 8);
    }

    // per-(lane,reg) sorted top-4 packed keys (ascending)
    unsigned int tk[4][4];
#pragma unroll
    for (int i = 0; i < 4; ++i)
#pragma unroll
        for (int q = 0; q < 4; ++q) tk[i][q] = 0xFFFFFFFFu;

    for (int ct = 0; ct < NN / CN; ++ct) {
        float sqb[4];
#pragma unroll
        for (int cc = 0; cc < 4; ++cc)
            sqb[cc] = sqv[(size_t)b * NN + ct * CN + cc * 16 + m] + 1024.0f;

        __syncthreads();
        if constexpr (PRE) {
#pragma unroll
            for (int l = 0; l < 4; ++l) {
                int f = (l * 4 + w) * 64 + lane;
                int r = f >> 4, p = f & 15;
                int c = p ^ (r & 7);
                gl2lds16(gb + (size_t)(ct * CN + r) * DD + c * 8, Bs + (l * 4 + w) * 512);
            }
        } else {
#pragma unroll
            for (int l = 0; l < 4; ++l) {
                int id = l * 256 + tid;
                int r = id >> 4, c = id & 15, p = c ^ (r & 7);
                const float4* src = reinterpret_cast<const float4*>(xb + (size_t)(ct * CN + r) * DD + c * 8);
                float4 v0 = src[0], v1 = src[1];
                short8 pk;
                pk[0] = (short)f2bf(v0.x); pk[1] = (short)f2bf(v0.y);
                pk[2] = (short)f2bf(v0.z); pk[3] = (short)f2bf(v0.w);
                pk[4] = (short)f2bf(v1.x); pk[5] = (short)f2bf(v1.y);
                pk[6] = (short)f2bf(v1.z); pk[7] = (short)f2bf(v1.w);
                *reinterpret_cast<short8*>(Bs + r * DD + p * 8) = pk;
            }
        }
        __syncthreads();

        float4v acc[4];
#pragma unroll
        for (int cc = 0; cc < 4; ++cc) acc[cc] = (float4v){0.f, 0.f, 0.f, 0.f};
#pragma unroll
        for (int kc = 0; kc < 4; ++kc) {
#pragma unroll
            for (int cc = 0; cc < 4; ++cc) {
                int rl = cc * 16 + m;
                int p = (kc * 4 + quad) ^ (m & 7);
                short8 bfrag = *reinterpret_cast<const short8*>(Bs + rl * DD + p * 8);
                acc[cc] = __builtin_amdgcn_mfma_f32_16x16x32_bf16(afrag[kc], bfrag, acc[cc], 0, 0, 0);
            }
        }

        // branchless epilogue: pack key, 7-op sorted-insert into top-4
#pragma unroll
        for (int cc = 0; cc < 4; ++cc) {
            unsigned int col = (unsigned int)(ct * CN + cc * 16 + m);
#pragma unroll
            for (int reg = 0; reg < 4; ++reg) {
                float scb = fmaf(-2.f, acc[cc][reg], sqb[cc]);   // positive: 1024 + d2 - sqr
                unsigned int key = (__builtin_bit_cast(unsigned int, scb) & 0xFFFFF800u) | col;
                unsigned int n;
                n = umn(tk[reg][0], key); key = umx(tk[reg][0], key); tk[reg][0] = n;
                n = umn(tk[reg][1], key); key = umx(tk[reg][1], key); tk[reg][1] = n;
                n = umn(tk[reg][2], key); key = umx(tk[reg][2], key); tk[reg][2] = n;
                tk[reg][3] = umn(tk[reg][3], key);
            }
        }
    }

    // ---- in-register merge: 16 lanes/quad-group x sorted-4 -> row top-8 ----
#pragma unroll
    for (int reg = 0; reg < 4; ++reg) {
        unsigned int e[8];
#pragma unroll
        for (int j = 0; j < 4; ++j) e[j] = tk[reg][j];
#pragma unroll
        for (int j = 4; j < 8; ++j) e[j] = 0xFFFFFFFFu;
#pragma unroll
        for (int st = 0; st < 4; ++st) {
            int mask = 1 << st;
            unsigned int rv[8];
#pragma unroll
            for (int j = 0; j < 8; ++j)
                rv[j] = (unsigned int)__shfl_xor((int)e[7 - j], mask, 64);
#pragma unroll
            for (int j = 0; j < 8; ++j) e[j] = umn(e[j], rv[j]);
            // bitonic sort-8 (ascending)
            CSU(e[0], e[4]); CSU(e[1], e[5]); CSU(e[2], e[6]); CSU(e[3], e[7]);
            CSU(e[0], e[2]); CSU(e[1], e[3]); CSU(e[4], e[6]); CSU(e[5], e[7]);
            CSU(e[0], e[1]); CSU(e[2], e[3]); CSU(e[4], e[5]); CSU(e[6], e[7]);
        }
        if (m == 0) {
            int row = 16 * w + quad * 4 + reg;
#pragma unroll
            for (int j = 0; j < 8; ++j) cand8[row * 8 + j] = e[j];
        }
    }
    __syncthreads();

    // ---- refine: exact fp64 distance for 8 survivors/row (self -> DBL_MAX) ----
    {
        int r = tid >> 2, q4 = tid & 3;
        int grow = row0 + r;
        int c0 = (int)(cand8[r * 8 + q4 * 2 + 0] & 0x7FFu);
        int c1 = (int)(cand8[r * 8 + q4 * 2 + 1] & 0x7FFu);
        const float* p0 = xb + (size_t)c0 * DD;
        const float* p1 = xb + (size_t)c1 * DD;
        const float* pr = xb + (size_t)grow * DD;
        double a0 = 0.0, a1 = 0.0;
#pragma unroll 4
        for (int d4 = 0; d4 < 32; ++d4) {
            float4 wv = *reinterpret_cast<const float4*>(pr + d4 * 4);
            float4 v0 = *reinterpret_cast<const float4*>(p0 + d4 * 4);
            float4 v1 = *reinterpret_cast<const float4*>(p1 + d4 * 4);
            double d;
            d = (double)wv.x - (double)v0.x; a0 += d * d;
            d = (double)wv.y - (double)v0.y; a0 += d * d;
            d = (double)wv.z - (double)v0.z; a0 += d * d;
            d = (double)wv.w - (double)v0.w; a0 += d * d;
            d = (double)wv.x - (double)v1.x; a1 += d * d;
            d = (double)wv.y - (double)v1.y; a1 += d * d;
            d = (double)wv.z - (double)v1.z; a1 += d * d;
            d = (double)wv.w - (double)v1.w; a1 += d * d;
        }
        refd[r * 8 + q4 * 2 + 0] = (c0 == grow) ? DBL_MAX : a0;
        refd[r * 8 + q4 * 2 + 1] = (c1 == grow) ? DBL_MAX : a1;
    }
    __syncthreads();

    // ---- final top-3 by (exact d2, idx) ----
    if (tid < RM) {
        int r = tid;
        double b0 = DBL_MAX, b1 = DBL_MAX, b2 = DBL_MAX;
        int i0 = 0x7fffffff, i1 = 0x7fffffff, i2 = 0x7fffffff;
        for (int e = 0; e < 8; ++e) {
            double dv = refd[r * 8 + e];
            int ix = (int)(cand8[r * 8 + e] & 0x7FFu);
            if (dv < b2 || (dv == b2 && ix < i2)) {
                b2 = dv; i2 = ix;
                if (b1 > b2 || (b1 == b2 && i1 > i2)) { double td = b1; b1 = b2; b2 = td; int tn = i1; i1 = i2; i2 = tn; }
                if (b0 > b1 || (b0 == b1 && i0 > i1)) { double td = b0; b0 = b1; b1 = td; int tn = i0; i0 = i1; i1 = tn; }
            }
        }
        best3[r * 3 + 0] = i0; best3[r * 3 + 1] = i1; best3[r * 3 + 2] = i2;
    }
    __syncthreads();

    // ---- output ----
    {
        int r = tid >> 2, q = tid & 3;
        float s = fminf(fmaxf(strength[0], 0.f), 1.f);
        const float* pa = xb + (size_t)(row0 + r) * DD + q * 32;
        const float* p1 = xb + (size_t)best3[r * 3 + 0] * DD + q * 32;
        const float* p2 = xb + (size_t)best3[r * 3 + 1] * DD + q * 32;
        const float* p3 = xb + (size_t)best3[r * 3 + 2] * DD + q * 32;
        float* po = out + ((size_t)b * NN + row0 + r) * DD + q * 32;
#pragma unroll
        for (int l = 0; l < 8; ++l) {
            float4 a  = *reinterpret_cast<const float4*>(pa + l * 4);
            float4 n1 = *reinterpret_cast<const float4*>(p1 + l * 4);
            float4 n2 = *reinterpret_cast<const float4*>(p2 + l * 4);
            float4 n3 = *reinterpret_cast<const float4*>(p3 + l * 4);
            float4 o;
            o.x = (1.f - s) * a.x + s * ((n1.x + n2.x + n3.x) / 3.f);
            o.y = (1.f - s) * a.y + s * ((n1.y + n2.y + n3.y) / 3.f);
            o.z = (1.f - s) * a.z + s * ((n1.z + n2.z + n3.z) / 3.f);
            o.w = (1.f - s) * a.w + s * ((n1.w + n2.w + n3.w) / 3.f);
            *reinterpret_cast<float4*>(po + l * 4) = o;
        }
    }
}

extern "C" void kernel_launch(void* const* d_in, const int* in_sizes, int n_in,
                              void* d_out, int out_size, void* d_ws, size_t ws_size,
                              hipStream_t stream) {
    const float* x = (const float*)d_in[0];
    const float* strength = (const float*)d_in[1];
    float* out = (float*)d_out;
    float* sq = (float*)d_ws;
    unsigned short* xb16 = (unsigned short*)((char*)d_ws + 256 * 1024);
    const size_t need = 256 * 1024 + (size_t)BB * NN * DD * sizeof(unsigned short);

    if (ws_size >= need) {
        prep_kernel<<<dim3((BB * NN * 4) / 256), 256, 0, stream>>>(x, xb16, sq);
        knn_kernel<true><<<dim3(NN / RM, BB), 256, 0, stream>>>(x, xb16, sq, strength, out);
    } else {
        sq_kernel<<<dim3((BB * NN * 4) / 256), 256, 0, stream>>>(x, sq);
        knn_kernel<false><<<dim3(NN / RM, BB), 256, 0, stream>>>(x, nullptr, sq, strength, out);
    }
}

// Round 5
// 204.108 us; speedup vs baseline: 3.6127x; 1.0458x over previous
//
#include <hip/hip_runtime.h>
#include <cfloat>

#define BB 32
#define NN 2048
#define DD 128
#define RM 64     // rows per block (4 waves x 16)
#define CN 64     // cols per tile

typedef __attribute__((ext_vector_type(8))) short short8;
typedef __attribute__((ext_vector_type(4))) float float4v;

__device__ __forceinline__ unsigned short f2bf(float f) {
    unsigned int u = __builtin_bit_cast(unsigned int, f);
    u += 0x7FFFu + ((u >> 16) & 1u);   // RNE
    return (unsigned short)(u >> 16);
}

__device__ __forceinline__ unsigned int umn(unsigned int a, unsigned int b) { return a < b ? a : b; }
__device__ __forceinline__ unsigned int umx(unsigned int a, unsigned int b) { return a > b ? a : b; }
#define CSU(a, b) { unsigned int _lo = umn(a, b), _hi = umx(a, b); (a) = _lo; (b) = _hi; }

// async global->LDS, 16B per lane. LDS dest is wave-uniform base + lane*16.
__device__ __forceinline__ void gl2lds16(const unsigned short* g, unsigned short* l) {
    __builtin_amdgcn_global_load_lds(
        (const __attribute__((address_space(1))) void*)g,
        (__attribute__((address_space(3))) void*)l, 16, 0, 0);
}

// fused: sq = sum(x^2) per row, and bf16 copy of x into workspace
__global__ __launch_bounds__(256) void prep_kernel(const float* __restrict__ x,
        unsigned short* __restrict__ xb16, float* __restrict__ sq) {
    int t = blockIdx.x * 256 + threadIdx.x;
    int row = t >> 2;
    int q = t & 3;
    const float4* xp = reinterpret_cast<const float4*>(x + (size_t)row * DD + q * 32);
    unsigned short* op = xb16 + (size_t)row * DD + q * 32;
    float acc = 0.f;
#pragma unroll
    for (int i = 0; i < 4; ++i) {
        float4 v0 = xp[2 * i], v1 = xp[2 * i + 1];
        acc += v0.x * v0.x + v0.y * v0.y + v0.z * v0.z + v0.w * v0.w;
        acc += v1.x * v1.x + v1.y * v1.y + v1.z * v1.z + v1.w * v1.w;
        short8 pk;
        pk[0] = (short)f2bf(v0.x); pk[1] = (short)f2bf(v0.y);
        pk[2] = (short)f2bf(v0.z); pk[3] = (short)f2bf(v0.w);
        pk[4] = (short)f2bf(v1.x); pk[5] = (short)f2bf(v1.y);
        pk[6] = (short)f2bf(v1.z); pk[7] = (short)f2bf(v1.w);
        *reinterpret_cast<short8*>(op + i * 8) = pk;
    }
    acc += __shfl_xor(acc, 1);
    acc += __shfl_xor(acc, 2);
    if (q == 0) sq[row] = acc;
}

__global__ __launch_bounds__(256) void sq_kernel(const float* __restrict__ x,
                                                 float* __restrict__ sq) {
    int t = blockIdx.x * 256 + threadIdx.x;
    int row = t >> 2;
    int q = t & 3;
    const float4* xp = reinterpret_cast<const float4*>(x + (size_t)row * DD + q * 32);
    float acc = 0.f;
#pragma unroll
    for (int i = 0; i < 8; ++i) {
        float4 v = xp[i];
        acc += v.x * v.x + v.y * v.y + v.z * v.z + v.w * v.w;
    }
    acc += __shfl_xor(acc, 1);
    acc += __shfl_xor(acc, 2);
    if (q == 0) sq[row] = acc;
}

// B tile layout (per buffer): row r (0..63), 16 chunks of 8 bf16; chunk c at pos c^(r&7).
template<bool PRE>
__global__ __launch_bounds__(256, 4) void knn_kernel(const float* __restrict__ x,
        const unsigned short* __restrict__ xb16g,
        const float* __restrict__ sqv, const float* __restrict__ strength,
        float* __restrict__ out) {
    __shared__ __align__(16) unsigned short btile[2 * CN * DD]; // 32 KB, double-buffered
    __shared__ unsigned int cand8[RM * 8];                      // 2 KB => 34 KB total => 4 blocks/CU

    const int b = blockIdx.x;            // batch on fast dim: all 32 row-blocks of a batch share an XCD
    const int row0 = blockIdx.y * RM;
    const int tid = threadIdx.x;
    const int w = tid >> 6;
    const int lane = tid & 63;
    const int m = lane & 15;
    const int quad = lane >> 4;
    const float* __restrict__ xb = x + (size_t)b * NN * DD;
    const unsigned short* __restrict__ gb = PRE ? xb16g + (size_t)b * NN * DD : nullptr;

    // ---- A fragments direct from global (no LDS round-trip) ----
    // lane (w,m,quad), kc: A[row=row0+16w+m][k=kc*32+quad*8 .. +8] = 16B contiguous
    short8 afrag[4];
    if constexpr (PRE) {
#pragma unroll
        for (int kc = 0; kc < 4; ++kc)
            afrag[kc] = *reinterpret_cast<const short8*>(
                gb + (size_t)(row0 + 16 * w + m) * DD + kc * 32 + quad * 8);
    } else {
#pragma unroll
        for (int kc = 0; kc < 4; ++kc) {
            const float4* src = reinterpret_cast<const float4*>(
                xb + (size_t)(row0 + 16 * w + m) * DD + kc * 32 + quad * 8);
            float4 v0 = src[0], v1 = src[1];
            short8 pk;
            pk[0] = (short)f2bf(v0.x); pk[1] = (short)f2bf(v0.y);
            pk[2] = (short)f2bf(v0.z); pk[3] = (short)f2bf(v0.w);
            pk[4] = (short)f2bf(v1.x); pk[5] = (short)f2bf(v1.y);
            pk[6] = (short)f2bf(v1.z); pk[7] = (short)f2bf(v1.w);
            afrag[kc] = pk;
        }
    }

    // ---- stage tile 0 into buffer 0 ----
    {
        unsigned short* buf = btile;
        if constexpr (PRE) {
#pragma unroll
            for (int l = 0; l < 4; ++l) {
                int f = (l * 4 + w) * 64 + lane;
                int r = f >> 4, p = f & 15;
                int c = p ^ (r & 7);
                gl2lds16(gb + (size_t)r * DD + c * 8, buf + (l * 4 + w) * 512);
            }
        } else {
#pragma unroll
            for (int l = 0; l < 4; ++l) {
                int id = l * 256 + tid;
                int r = id >> 4, c = id & 15, p = c ^ (r & 7);
                const float4* src = reinterpret_cast<const float4*>(xb + (size_t)r * DD + c * 8);
                float4 v0 = src[0], v1 = src[1];
                short8 pk;
                pk[0] = (short)f2bf(v0.x); pk[1] = (short)f2bf(v0.y);
                pk[2] = (short)f2bf(v0.z); pk[3] = (short)f2bf(v0.w);
                pk[4] = (short)f2bf(v1.x); pk[5] = (short)f2bf(v1.y);
                pk[6] = (short)f2bf(v1.z); pk[7] = (short)f2bf(v1.w);
                *reinterpret_cast<short8*>(buf + r * DD + p * 8) = pk;
            }
        }
    }
    __syncthreads();   // vmcnt/lgkm drained: buffer 0 ready

    unsigned int tk[4][4];
#pragma unroll
    for (int i = 0; i < 4; ++i)
#pragma unroll
        for (int q = 0; q < 4; ++q) tk[i][q] = 0xFFFFFFFFu;

    for (int ct = 0; ct < NN / CN; ++ct) {
        unsigned short* cur = btile + (size_t)(ct & 1) * CN * DD;
        unsigned short* nxt = btile + (size_t)((ct + 1) & 1) * CN * DD;

        // issue async stage of tile ct+1 (completes by this iteration's end barrier)
        if (ct + 1 < NN / CN) {
            int cb = (ct + 1) * CN;
            if constexpr (PRE) {
#pragma unroll
                for (int l = 0; l < 4; ++l) {
                    int f = (l * 4 + w) * 64 + lane;
                    int r = f >> 4, p = f & 15;
                    int c = p ^ (r & 7);
                    gl2lds16(gb + (size_t)(cb + r) * DD + c * 8, nxt + (l * 4 + w) * 512);
                }
            } else {
#pragma unroll
                for (int l = 0; l < 4; ++l) {
                    int id = l * 256 + tid;
                    int r = id >> 4, c = id & 15, p = c ^ (r & 7);
                    const float4* src = reinterpret_cast<const float4*>(xb + (size_t)(cb + r) * DD + c * 8);
                    float4 v0 = src[0], v1 = src[1];
                    short8 pk;
                    pk[0] = (short)f2bf(v0.x); pk[1] = (short)f2bf(v0.y);
                    pk[2] = (short)f2bf(v0.z); pk[3] = (short)f2bf(v0.w);
                    pk[4] = (short)f2bf(v1.x); pk[5] = (short)f2bf(v1.y);
                    pk[6] = (short)f2bf(v1.z); pk[7] = (short)f2bf(v1.w);
                    *reinterpret_cast<short8*>(nxt + r * DD + p * 8) = pk;
                }
            }
        }

        float sqb[4];
#pragma unroll
        for (int cc = 0; cc < 4; ++cc)
            sqb[cc] = sqv[(size_t)b * NN + ct * CN + cc * 16 + m] + 1024.0f;

        float4v acc[4];
#pragma unroll
        for (int cc = 0; cc < 4; ++cc) acc[cc] = (float4v){0.f, 0.f, 0.f, 0.f};
#pragma unroll
        for (int kc = 0; kc < 4; ++kc) {
#pragma unroll
            for (int cc = 0; cc < 4; ++cc) {
                int rl = cc * 16 + m;
                int p = (kc * 4 + quad) ^ (m & 7);
                short8 bfrag = *reinterpret_cast<const short8*>(cur + rl * DD + p * 8);
                acc[cc] = __builtin_amdgcn_mfma_f32_16x16x32_bf16(afrag[kc], bfrag, acc[cc], 0, 0, 0);
            }
        }

        // branchless epilogue: pack key, sorted-insert into top-4
#pragma unroll
        for (int cc = 0; cc < 4; ++cc) {
            unsigned int col = (unsigned int)(ct * CN + cc * 16 + m);
#pragma unroll
            for (int reg = 0; reg < 4; ++reg) {
                float scb = fmaf(-2.f, acc[cc][reg], sqb[cc]);   // 1024 + d2 - sqr > 0
                unsigned int key = (__builtin_bit_cast(unsigned int, scb) & 0xFFFFF800u) | col;
                unsigned int n;
                n = umn(tk[reg][0], key); key = umx(tk[reg][0], key); tk[reg][0] = n;
                n = umn(tk[reg][1], key); key = umx(tk[reg][1], key); tk[reg][1] = n;
                n = umn(tk[reg][2], key); key = umx(tk[reg][2], key); tk[reg][2] = n;
                tk[reg][3] = umn(tk[reg][3], key);
            }
        }

        __syncthreads();   // drains stage(ct+1) vmcnt; all waves done reading cur
    }

    // ---- in-register merge: 16 lanes/quad-group x sorted-4 -> row top-8 ----
#pragma unroll
    for (int reg = 0; reg < 4; ++reg) {
        unsigned int e[8];
#pragma unroll
        for (int j = 0; j < 4; ++j) e[j] = tk[reg][j];
#pragma unroll
        for (int j = 4; j < 8; ++j) e[j] = 0xFFFFFFFFu;
#pragma unroll
        for (int st = 0; st < 4; ++st) {
            int mask = 1 << st;
            unsigned int rv[8];
#pragma unroll
            for (int j = 0; j < 8; ++j)
                rv[j] = (unsigned int)__shfl_xor((int)e[7 - j], mask, 64);
#pragma unroll
            for (int j = 0; j < 8; ++j) e[j] = umn(e[j], rv[j]);
            CSU(e[0], e[4]); CSU(e[1], e[5]); CSU(e[2], e[6]); CSU(e[3], e[7]);
            CSU(e[0], e[2]); CSU(e[1], e[3]); CSU(e[4], e[6]); CSU(e[5], e[7]);
            CSU(e[0], e[1]); CSU(e[2], e[3]); CSU(e[4], e[5]); CSU(e[6], e[7]);
        }
        if (m == 0) {
            int row = 16 * w + quad * 4 + reg;
#pragma unroll
            for (int j = 0; j < 8; ++j) cand8[row * 8 + j] = e[j];
        }
    }
    __syncthreads();

    // alias btile for refine scratch (all tile reads done)
    double* refd = reinterpret_cast<double*>(btile);           // 4 KB
    int* best3 = reinterpret_cast<int*>(btile) + 1024;         // next 768 B

    // ---- refine: exact fp64 distance for 8 survivors/row (self -> DBL_MAX) ----
    {
        int r = tid >> 2, q4 = tid & 3;
        int grow = row0 + r;
        int c0 = (int)(cand8[r * 8 + q4 * 2 + 0] & 0x7FFu);
        int c1 = (int)(cand8[r * 8 + q4 * 2 + 1] & 0x7FFu);
        const float* p0 = xb + (size_t)c0 * DD;
        const float* p1 = xb + (size_t)c1 * DD;
        const float* pr = xb + (size_t)grow * DD;
        double a0 = 0.0, a1 = 0.0;
#pragma unroll 4
        for (int d4 = 0; d4 < 32; ++d4) {
            float4 wv = *reinterpret_cast<const float4*>(pr + d4 * 4);
            float4 v0 = *reinterpret_cast<const float4*>(p0 + d4 * 4);
            float4 v1 = *reinterpret_cast<const float4*>(p1 + d4 * 4);
            double d;
            d = (double)wv.x - (double)v0.x; a0 += d * d;
            d = (double)wv.y - (double)v0.y; a0 += d * d;
            d = (double)wv.z - (double)v0.z; a0 += d * d;
            d = (double)wv.w - (double)v0.w; a0 += d * d;
            d = (double)wv.x - (double)v1.x; a1 += d * d;
            d = (double)wv.y - (double)v1.y; a1 += d * d;
            d = (double)wv.z - (double)v1.z; a1 += d * d;
            d = (double)wv.w - (double)v1.w; a1 += d * d;
        }
        refd[r * 8 + q4 * 2 + 0] = (c0 == grow) ? DBL_MAX : a0;
        refd[r * 8 + q4 * 2 + 1] = (c1 == grow) ? DBL_MAX : a1;
    }
    __syncthreads();

    // ---- final top-3 by (exact d2, idx) ----
    if (tid < RM) {
        int r = tid;
        double b0 = DBL_MAX, b1 = DBL_MAX, b2 = DBL_MAX;
        int i0 = 0x7fffffff, i1 = 0x7fffffff, i2 = 0x7fffffff;
        for (int e = 0; e < 8; ++e) {
            double dv = refd[r * 8 + e];
            int ix = (int)(cand8[r * 8 + e] & 0x7FFu);
            if (dv < b2 || (dv == b2 && ix < i2)) {
                b2 = dv; i2 = ix;
                if (b1 > b2 || (b1 == b2 && i1 > i2)) { double td = b1; b1 = b2; b2 = td; int tn = i1; i1 = i2; i2 = tn; }
                if (b0 > b1 || (b0 == b1 && i0 > i1)) { double td = b0; b0 = b1; b1 = td; int tn = i0; i0 = i1; i1 = tn; }
            }
        }
        best3[r * 3 + 0] = i0; best3[r * 3 + 1] = i1; best3[r * 3 + 2] = i2;
    }
    __syncthreads();

    // ---- output ----
    {
        int r = tid >> 2, q = tid & 3;
        float s = fminf(fmaxf(strength[0], 0.f), 1.f);
        const float* pa = xb + (size_t)(row0 + r) * DD + q * 32;
        const float* p1 = xb + (size_t)best3[r * 3 + 0] * DD + q * 32;
        const float* p2 = xb + (size_t)best3[r * 3 + 1] * DD + q * 32;
        const float* p3 = xb + (size_t)best3[r * 3 + 2] * DD + q * 32;
        float* po = out + ((size_t)b * NN + row0 + r) * DD + q * 32;
#pragma unroll
        for (int l = 0; l < 8; ++l) {
            float4 a  = *reinterpret_cast<const float4*>(pa + l * 4);
            float4 n1 = *reinterpret_cast<const float4*>(p1 + l * 4);
            float4 n2 = *reinterpret_cast<const float4*>(p2 + l * 4);
            float4 n3 = *reinterpret_cast<const float4*>(p3 + l * 4);
            float4 o;
            o.x = (1.f - s) * a.x + s * ((n1.x + n2.x + n3.x) / 3.f);
            o.y = (1.f - s) * a.y + s * ((n1.y + n2.y + n3.y) / 3.f);
            o.z = (1.f - s) * a.z + s * ((n1.z + n2.z + n3.z) / 3.f);
            o.w = (1.f - s) * a.w + s * ((n1.w + n2.w + n3.w) / 3.f);
            *reinterpret_cast<float4*>(po + l * 4) = o;
        }
    }
}

extern "C" void kernel_launch(void* const* d_in, const int* in_sizes, int n_in,
                              void* d_out, int out_size, void* d_ws, size_t ws_size,
                              hipStream_t stream) {
    const float* x = (const float*)d_in[0];
    const float* strength = (const float*)d_in[1];
    float* out = (float*)d_out;
    float* sq = (float*)d_ws;
    unsigned short* xb16 = (unsigned short*)((char*)d_ws + 256 * 1024);
    const size_t need = 256 * 1024 + (size_t)BB * NN * DD * sizeof(unsigned short);

    if (ws_size >= need) {
        prep_kernel<<<dim3((BB * NN * 4) / 256), 256, 0, stream>>>(x, xb16, sq);
        knn_kernel<true><<<dim3(BB, NN / RM), 256, 0, stream>>>(x, xb16, sq, strength, out);
    } else {
        sq_kernel<<<dim3((BB * NN * 4) / 256), 256, 0, stream>>>(x, sq);
        knn_kernel<false><<<dim3(BB, NN / RM), 256, 0, stream>>>(x, nullptr, sq, strength, out);
    }
}

// Round 6
// 200.849 us; speedup vs baseline: 3.6713x; 1.0162x over previous
//
#include <hip/hip_runtime.h>
#include <cfloat>

#define BB 32
#define NN 2048
#define DD 128
#define RM 128    // rows per block (4 waves x 32 rows/wave)
#define CN 64     // cols per tile

typedef __attribute__((ext_vector_type(8))) short short8;
typedef __attribute__((ext_vector_type(4))) float float4v;

__device__ __forceinline__ unsigned short f2bf(float f) {
    unsigned int u = __builtin_bit_cast(unsigned int, f);
    u += 0x7FFFu + ((u >> 16) & 1u);   // RNE
    return (unsigned short)(u >> 16);
}

__device__ __forceinline__ unsigned int umn(unsigned int a, unsigned int b) { return a < b ? a : b; }
__device__ __forceinline__ unsigned int umx(unsigned int a, unsigned int b) { return a > b ? a : b; }
#define CSU(a, b) { unsigned int _lo = umn(a, b), _hi = umx(a, b); (a) = _lo; (b) = _hi; }

// async global->LDS, 16B per lane. LDS dest is wave-uniform base + lane*16.
__device__ __forceinline__ void gl2lds16(const unsigned short* g, unsigned short* l) {
    __builtin_amdgcn_global_load_lds(
        (const __attribute__((address_space(1))) void*)g,
        (__attribute__((address_space(3))) void*)l, 16, 0, 0);
}

// fused: sq = sum(x^2) per row, and bf16 copy of x into workspace
__global__ __launch_bounds__(256) void prep_kernel(const float* __restrict__ x,
        unsigned short* __restrict__ xb16, float* __restrict__ sq) {
    int t = blockIdx.x * 256 + threadIdx.x;
    int row = t >> 2;
    int q = t & 3;
    const float4* xp = reinterpret_cast<const float4*>(x + (size_t)row * DD + q * 32);
    unsigned short* op = xb16 + (size_t)row * DD + q * 32;
    float acc = 0.f;
#pragma unroll
    for (int i = 0; i < 4; ++i) {
        float4 v0 = xp[2 * i], v1 = xp[2 * i + 1];
        acc += v0.x * v0.x + v0.y * v0.y + v0.z * v0.z + v0.w * v0.w;
        acc += v1.x * v1.x + v1.y * v1.y + v1.z * v1.z + v1.w * v1.w;
        short8 pk;
        pk[0] = (short)f2bf(v0.x); pk[1] = (short)f2bf(v0.y);
        pk[2] = (short)f2bf(v0.z); pk[3] = (short)f2bf(v0.w);
        pk[4] = (short)f2bf(v1.x); pk[5] = (short)f2bf(v1.y);
        pk[6] = (short)f2bf(v1.z); pk[7] = (short)f2bf(v1.w);
        *reinterpret_cast<short8*>(op + i * 8) = pk;
    }
    acc += __shfl_xor(acc, 1);
    acc += __shfl_xor(acc, 2);
    if (q == 0) sq[row] = acc;
}

__global__ __launch_bounds__(256) void sq_kernel(const float* __restrict__ x,
                                                 float* __restrict__ sq) {
    int t = blockIdx.x * 256 + threadIdx.x;
    int row = t >> 2;
    int q = t & 3;
    const float4* xp = reinterpret_cast<const float4*>(x + (size_t)row * DD + q * 32);
    float acc = 0.f;
#pragma unroll
    for (int i = 0; i < 8; ++i) {
        float4 v = xp[i];
        acc += v.x * v.x + v.y * v.y + v.z * v.z + v.w * v.w;
    }
    acc += __shfl_xor(acc, 1);
    acc += __shfl_xor(acc, 2);
    if (q == 0) sq[row] = acc;
}

// B tile layout (per buffer): row r (0..63), 16 chunks of 8 bf16; chunk c at pos c^(r&7).
template<bool PRE>
__global__ __launch_bounds__(256, 2) void knn_kernel(const float* __restrict__ x,
        const unsigned short* __restrict__ xb16g,
        const float* __restrict__ sqv, const float* __restrict__ strength,
        float* __restrict__ out) {
    __shared__ __align__(16) unsigned short btile[2 * CN * DD]; // 32 KB, double-buffered
    __shared__ unsigned int cand8[RM * 8];                      // 4 KB => 36 KB => 2 blocks/CU (grid-limited)

    const int b = blockIdx.x;            // flat%8 = b%8: all 16 row-blocks of a batch share an XCD
    const int row0 = blockIdx.y * RM;
    const int tid = threadIdx.x;
    const int w = tid >> 6;
    const int lane = tid & 63;
    const int m = lane & 15;
    const int quad = lane >> 4;
    const float* __restrict__ xb = x + (size_t)b * NN * DD;
    const unsigned short* __restrict__ gb = PRE ? xb16g + (size_t)b * NN * DD : nullptr;

    // ---- A fragments direct from global: 2 row-groups x 4 k-chunks per lane ----
    // A[row = row0 + 32w + rg*16 + m][k = kc*32 + quad*8 .. +8] = 16B contiguous
    short8 afrag[2][4];
    if constexpr (PRE) {
#pragma unroll
        for (int rg = 0; rg < 2; ++rg)
#pragma unroll
            for (int kc = 0; kc < 4; ++kc)
                afrag[rg][kc] = *reinterpret_cast<const short8*>(
                    gb + (size_t)(row0 + 32 * w + rg * 16 + m) * DD + kc * 32 + quad * 8);
    } else {
#pragma unroll
        for (int rg = 0; rg < 2; ++rg)
#pragma unroll
            for (int kc = 0; kc < 4; ++kc) {
                const float4* src = reinterpret_cast<const float4*>(
                    xb + (size_t)(row0 + 32 * w + rg * 16 + m) * DD + kc * 32 + quad * 8);
                float4 v0 = src[0], v1 = src[1];
                short8 pk;
                pk[0] = (short)f2bf(v0.x); pk[1] = (short)f2bf(v0.y);
                pk[2] = (short)f2bf(v0.z); pk[3] = (short)f2bf(v0.w);
                pk[4] = (short)f2bf(v1.x); pk[5] = (short)f2bf(v1.y);
                pk[6] = (short)f2bf(v1.z); pk[7] = (short)f2bf(v1.w);
                afrag[rg][kc] = pk;
            }
    }

    // ---- stage tile 0 into buffer 0 ----
    {
        unsigned short* buf = btile;
        if constexpr (PRE) {
#pragma unroll
            for (int l = 0; l < 4; ++l) {
                int f = (l * 4 + w) * 64 + lane;
                int r = f >> 4, p = f & 15;
                int c = p ^ (r & 7);
                gl2lds16(gb + (size_t)r * DD + c * 8, buf + (l * 4 + w) * 512);
            }
        } else {
#pragma unroll
            for (int l = 0; l < 4; ++l) {
                int id = l * 256 + tid;
                int r = id >> 4, c = id & 15, p = c ^ (r & 7);
                const float4* src = reinterpret_cast<const float4*>(xb + (size_t)r * DD + c * 8);
                float4 v0 = src[0], v1 = src[1];
                short8 pk;
                pk[0] = (short)f2bf(v0.x); pk[1] = (short)f2bf(v0.y);
                pk[2] = (short)f2bf(v0.z); pk[3] = (short)f2bf(v0.w);
                pk[4] = (short)f2bf(v1.x); pk[5] = (short)f2bf(v1.y);
                pk[6] = (short)f2bf(v1.z); pk[7] = (short)f2bf(v1.w);
                *reinterpret_cast<short8*>(buf + r * DD + p * 8) = pk;
            }
        }
    }
    __syncthreads();   // buffer 0 ready

    // per-(lane, rg, reg) sorted top-4 packed keys (ascending).
    // Lossless: only 3 keys can be globally smaller than true rank-3, so it
    // can never be evicted from its lane-class top-4.
    unsigned int tk[2][4][4];
#pragma unroll
    for (int rg = 0; rg < 2; ++rg)
#pragma unroll
        for (int i = 0; i < 4; ++i)
#pragma unroll
            for (int q = 0; q < 4; ++q) tk[rg][i][q] = 0xFFFFFFFFu;

    for (int ct = 0; ct < NN / CN; ++ct) {
        unsigned short* cur = btile + (size_t)(ct & 1) * CN * DD;
        unsigned short* nxt = btile + (size_t)((ct + 1) & 1) * CN * DD;

        // issue async stage of tile ct+1; its vmcnt drains at this iter's end barrier,
        // one full compute-phase after issue.
        if (ct + 1 < NN / CN) {
            int cb = (ct + 1) * CN;
            if constexpr (PRE) {
#pragma unroll
                for (int l = 0; l < 4; ++l) {
                    int f = (l * 4 + w) * 64 + lane;
                    int r = f >> 4, p = f & 15;
                    int c = p ^ (r & 7);
                    gl2lds16(gb + (size_t)(cb + r) * DD + c * 8, nxt + (l * 4 + w) * 512);
                }
            } else {
#pragma unroll
                for (int l = 0; l < 4; ++l) {
                    int id = l * 256 + tid;
                    int r = id >> 4, c = id & 15, p = c ^ (r & 7);
                    const float4* src = reinterpret_cast<const float4*>(xb + (size_t)(cb + r) * DD + c * 8);
                    float4 v0 = src[0], v1 = src[1];
                    short8 pk;
                    pk[0] = (short)f2bf(v0.x); pk[1] = (short)f2bf(v0.y);
                    pk[2] = (short)f2bf(v0.z); pk[3] = (short)f2bf(v0.w);
                    pk[4] = (short)f2bf(v1.x); pk[5] = (short)f2bf(v1.y);
                    pk[6] = (short)f2bf(v1.z); pk[7] = (short)f2bf(v1.w);
                    *reinterpret_cast<short8*>(nxt + r * DD + p * 8) = pk;
                }
            }
        }

        float sqb[4];
#pragma unroll
        for (int cc = 0; cc < 4; ++cc)
            sqb[cc] = sqv[(size_t)b * NN + ct * CN + cc * 16 + m] + 1024.0f;

        // ---- 32 MFMAs from 16 b128 reads (reuse=2 via 2 row-groups) ----
        float4v acc[2][4];
#pragma unroll
        for (int rg = 0; rg < 2; ++rg)
#pragma unroll
            for (int cc = 0; cc < 4; ++cc) acc[rg][cc] = (float4v){0.f, 0.f, 0.f, 0.f};
#pragma unroll
        for (int kc = 0; kc < 4; ++kc) {
            short8 bfrag[4];
#pragma unroll
            for (int cc = 0; cc < 4; ++cc) {
                int rl = cc * 16 + m;
                int p = (kc * 4 + quad) ^ (m & 7);
                bfrag[cc] = *reinterpret_cast<const short8*>(cur + rl * DD + p * 8);
            }
#pragma unroll
            for (int rg = 0; rg < 2; ++rg)
#pragma unroll
                for (int cc = 0; cc < 4; ++cc)
                    acc[rg][cc] = __builtin_amdgcn_mfma_f32_16x16x32_bf16(
                        afrag[rg][kc], bfrag[cc], acc[rg][cc], 0, 0, 0);
        }

        // ---- branchless selection: pack key, sorted-insert into top-4 ----
#pragma unroll
        for (int cc = 0; cc < 4; ++cc) {
            unsigned int col = (unsigned int)(ct * CN + cc * 16 + m);
#pragma unroll
            for (int rg = 0; rg < 2; ++rg)
#pragma unroll
                for (int reg = 0; reg < 4; ++reg) {
                    float scb = fmaf(-2.f, acc[rg][cc][reg], sqb[cc]);   // 1024 + d2 - sqr > 0
                    unsigned int key = (__builtin_bit_cast(unsigned int, scb) & 0xFFFFF800u) | col;
                    unsigned int n;
                    n = umn(tk[rg][reg][0], key); key = umx(tk[rg][reg][0], key); tk[rg][reg][0] = n;
                    n = umn(tk[rg][reg][1], key); key = umx(tk[rg][reg][1], key); tk[rg][reg][1] = n;
                    n = umn(tk[rg][reg][2], key); key = umx(tk[rg][reg][2], key); tk[rg][reg][2] = n;
                    tk[rg][reg][3] = umn(tk[rg][reg][3], key);
                }
        }

        __syncthreads();   // drains stage(ct+1); all waves done reading cur
    }

    // ---- in-register merge: 16 lanes/quad-group x sorted-4 -> row top-8 ----
#pragma unroll
    for (int rg = 0; rg < 2; ++rg)
#pragma unroll
        for (int reg = 0; reg < 4; ++reg) {
            unsigned int e[8];
#pragma unroll
            for (int j = 0; j < 4; ++j) e[j] = tk[rg][reg][j];
#pragma unroll
            for (int j = 4; j < 8; ++j) e[j] = 0xFFFFFFFFu;
#pragma unroll
            for (int st = 0; st < 4; ++st) {
                int mask = 1 << st;
                unsigned int rv[8];
#pragma unroll
                for (int j = 0; j < 8; ++j)
                    rv[j] = (unsigned int)__shfl_xor((int)e[7 - j], mask, 64);
#pragma unroll
                for (int j = 0; j < 8; ++j) e[j] = umn(e[j], rv[j]);
                CSU(e[0], e[4]); CSU(e[1], e[5]); CSU(e[2], e[6]); CSU(e[3], e[7]);
                CSU(e[0], e[2]); CSU(e[1], e[3]); CSU(e[4], e[6]); CSU(e[5], e[7]);
                CSU(e[0], e[1]); CSU(e[2], e[3]); CSU(e[4], e[5]); CSU(e[6], e[7]);
            }
            if (m == 0) {
                int row = 32 * w + rg * 16 + quad * 4 + reg;
#pragma unroll
                for (int j = 0; j < 8; ++j) cand8[row * 8 + j] = e[j];
            }
        }
    __syncthreads();

    // alias btile for refine scratch (all tile reads done)
    double* refd = reinterpret_cast<double*>(btile);           // 8 KB
    int* best3 = reinterpret_cast<int*>(btile) + 2048;         // next 1.5 KB

    // ---- refine: exact fp64 distance; 2 threads/row x 4 candidates ----
    {
        int r = tid >> 1, h = tid & 1;
        int grow = row0 + r;
        int ci[4];
#pragma unroll
        for (int j = 0; j < 4; ++j) ci[j] = (int)(cand8[r * 8 + h * 4 + j] & 0x7FFu);
        const float* pr = xb + (size_t)grow * DD;
        const float* pc[4];
#pragma unroll
        for (int j = 0; j < 4; ++j) pc[j] = xb + (size_t)ci[j] * DD;
        double a[4] = {0.0, 0.0, 0.0, 0.0};
#pragma unroll 4
        for (int d4 = 0; d4 < 32; ++d4) {
            float4 wv = *reinterpret_cast<const float4*>(pr + d4 * 4);
#pragma unroll
            for (int j = 0; j < 4; ++j) {
                float4 v = *reinterpret_cast<const float4*>(pc[j] + d4 * 4);
                double d;
                d = (double)wv.x - (double)v.x; a[j] += d * d;
                d = (double)wv.y - (double)v.y; a[j] += d * d;
                d = (double)wv.z - (double)v.z; a[j] += d * d;
                d = (double)wv.w - (double)v.w; a[j] += d * d;
            }
        }
#pragma unroll
        for (int j = 0; j < 4; ++j)
            refd[r * 8 + h * 4 + j] = (ci[j] == grow) ? DBL_MAX : a[j];
    }
    __syncthreads();

    // ---- final top-3 by (exact d2, idx) ----
    if (tid < RM) {
        int r = tid;
        double b0 = DBL_MAX, b1 = DBL_MAX, b2 = DBL_MAX;
        int i0 = 0x7fffffff, i1 = 0x7fffffff, i2 = 0x7fffffff;
        for (int e = 0; e < 8; ++e) {
            double dv = refd[r * 8 + e];
            int ix = (int)(cand8[r * 8 + e] & 0x7FFu);
            if (dv < b2 || (dv == b2 && ix < i2)) {
                b2 = dv; i2 = ix;
                if (b1 > b2 || (b1 == b2 && i1 > i2)) { double td = b1; b1 = b2; b2 = td; int tn = i1; i1 = i2; i2 = tn; }
                if (b0 > b1 || (b0 == b1 && i0 > i1)) { double td = b0; b0 = b1; b1 = td; int tn = i0; i0 = i1; i1 = tn; }
            }
        }
        best3[r * 3 + 0] = i0; best3[r * 3 + 1] = i1; best3[r * 3 + 2] = i2;
    }
    __syncthreads();

    // ---- output: 2 threads/row x 64 floats ----
    {
        int r = tid >> 1, q = tid & 1;
        float s = fminf(fmaxf(strength[0], 0.f), 1.f);
        const float* pa = xb + (size_t)(row0 + r) * DD + q * 64;
        const float* p1 = xb + (size_t)best3[r * 3 + 0] * DD + q * 64;
        const float* p2 = xb + (size_t)best3[r * 3 + 1] * DD + q * 64;
        const float* p3 = xb + (size_t)best3[r * 3 + 2] * DD + q * 64;
        float* po = out + ((size_t)b * NN + row0 + r) * DD + q * 64;
#pragma unroll
        for (int l = 0; l < 16; ++l) {
            float4 a  = *reinterpret_cast<const float4*>(pa + l * 4);
            float4 n1 = *reinterpret_cast<const float4*>(p1 + l * 4);
            float4 n2 = *reinterpret_cast<const float4*>(p2 + l * 4);
            float4 n3 = *reinterpret_cast<const float4*>(p3 + l * 4);
            float4 o;
            o.x = (1.f - s) * a.x + s * ((n1.x + n2.x + n3.x) / 3.f);
            o.y = (1.f - s) * a.y + s * ((n1.y + n2.y + n3.y) / 3.f);
            o.z = (1.f - s) * a.z + s * ((n1.z + n2.z + n3.z) / 3.f);
            o.w = (1.f - s) * a.w + s * ((n1.w + n2.w + n3.w) / 3.f);
            *reinterpret_cast<float4*>(po + l * 4) = o;
        }
    }
}

extern "C" void kernel_launch(void* const* d_in, const int* in_sizes, int n_in,
                              void* d_out, int out_size, void* d_ws, size_t ws_size,
                              hipStream_t stream) {
    const float* x = (const float*)d_in[0];
    const float* strength = (const float*)d_in[1];
    float* out = (float*)d_out;
    float* sq = (float*)d_ws;
    unsigned short* xb16 = (unsigned short*)((char*)d_ws + 256 * 1024);
    const size_t need = 256 * 1024 + (size_t)BB * NN * DD * sizeof(unsigned short);

    if (ws_size >= need) {
        prep_kernel<<<dim3((BB * NN * 4) / 256), 256, 0, stream>>>(x, xb16, sq);
        knn_kernel<true><<<dim3(BB, NN / RM), 256, 0, stream>>>(x, xb16, sq, strength, out);
    } else {
        sq_kernel<<<dim3((BB * NN * 4) / 256), 256, 0, stream>>>(x, sq);
        knn_kernel<false><<<dim3(BB, NN / RM), 256, 0, stream>>>(x, nullptr, sq, strength, out);
    }
}